// Round 1
// baseline (755.990 us; speedup 1.0000x reference)
//
#include <hip/hip_runtime.h>
#include <hip/hip_fp16.h>
#include <math.h>

#define NN 50000
#define NE 800000
#define TT 6
#define HID 48
#define NB 196   // (NN+255)/256
#define LR 65    // LDS row stride for 64 nodes (mod 32 == 1 -> conflict-free)

__device__ __forceinline__ float sigmoidf_(float x){ return 1.0f/(1.0f+__expf(-x)); }
__device__ __forceinline__ float tanhf_(float x){
  float xc = fminf(fmaxf(x,-15.f),15.f);
  float t = __expf(2.f*xc);
  return (t-1.f)/(t+1.f);
}
__device__ __forceinline__ unsigned f2bf(float x){
  unsigned u = __float_as_uint(x);
  return (u + 0x7fffu + ((u>>16)&1u)) >> 16;   // RNE to bf16
}
__device__ __forceinline__ unsigned pack2(float a, float b){
  return f2bf(a) | (f2bf(b)<<16);
}
__device__ __forceinline__ float bflo(unsigned u){ return __uint_as_float(u<<16); }
__device__ __forceinline__ float bfhi(unsigned u){ return __uint_as_float(u & 0xffff0000u); }
__device__ __forceinline__ unsigned f2h(float x){
  return (unsigned)__half_as_ushort(__float2half(x));   // RNE fp16
}
__device__ __forceinline__ float h2f(unsigned u){
  return __half2float(__ushort_as_half((unsigned short)(u & 0xffffu)));
}

struct U3 { unsigned x,y,z; };

// 256-thread inclusive block scan (4 waves of 64)
__device__ __forceinline__ int block_scan_incl(int x, int* wsum){
  int lane = threadIdx.x & 63, w = threadIdx.x >> 6;
  int v = x;
#pragma unroll
  for(int d=1; d<64; d<<=1){
    int u = __shfl_up(v, d, 64);
    if(lane >= d) v += u;
  }
  if(lane==63) wsum[w] = v;
  __syncthreads();
  int add = 0;
#pragma unroll
  for(int k=0;k<3;k++) if(w>k) add += wsum[k];
  return v + add;
}

// ---------------- setup: cnt init + GRU weight repack ----------------
// WxT [48][144]: WxT[k][gf] = W_ih[gf][k]   (x-side, transposed, gf-contiguous)
// Whg [6][48][24]: per (wv,k): whr(8) whz(8) whn(8) for features wv*8..wv*8+7
__global__ __launch_bounds__(256) void k_setup(int* cnt,
                                               const float* __restrict__ Wih, const float* __restrict__ Whh,
                                               float* WxT, float* Whg){
  int i = blockIdx.x*256+threadIdx.x;
  if(i<NN) cnt[i]=0;
  if(i < 48*144){
    int k = i/144, gf = i%144;
    WxT[i] = Wih[gf*48 + k];
  }
  if(i < 6*48*24){
    int wv = i/1152, r = i%1152;
    int k = r/24, c = r%24;
    int g = c>>3, j = c&7;
    int gf = g*48 + wv*8 + j;
    Whg[i] = Whh[gf*48 + k];
  }
}

// single atomic per edge: rank within destination bucket
__global__ __launch_bounds__(256) void k_cnt(const int* __restrict__ ei, int* cnt, int* pos){
  int e = blockIdx.x*256+threadIdx.x;
  if(e<NE){
    int c = ei[NE+e];
    pos[e] = atomicAdd(&cnt[c], 1);
  }
}

// phase A: per-block sums of cnt
__global__ __launch_bounds__(256) void k_partA(const int* __restrict__ cnt, int* bsum){
  __shared__ int wsum[4];
  int i = blockIdx.x*256+threadIdx.x;
  int x = (i<NN)? cnt[i] : 0;
  int lane = threadIdx.x & 63, w = threadIdx.x >> 6;
  int v = x;
#pragma unroll
  for(int m=32;m>=1;m>>=1) v += __shfl_xor(v, m, 64);
  if(lane==0) wsum[w]=v;
  __syncthreads();
  if(threadIdx.x==0) bsum[blockIdx.x] = wsum[0]+wsum[1]+wsum[2]+wsum[3];
}

// phase B: exclusive scan of 196 block sums
__global__ __launch_bounds__(256) void k_midB(const int* __restrict__ bsum, int* bpre, int* offs){
  __shared__ int wsum[4];
  int t = threadIdx.x;
  int x = (t<NB)? bsum[t] : 0;
  int incl = block_scan_incl(x, wsum);
  if(t<NB) bpre[t] = incl - x;
  if(t==255) offs[NN] = incl;   // total
}

// phase C: per-block exclusive scan of cnt + bpre -> offs
__global__ __launch_bounds__(256) void k_offsC(const int* __restrict__ cnt, const int* __restrict__ bpre,
                                               int* offs){
  __shared__ int wsum[4];
  int i = blockIdx.x*256+threadIdx.x;
  int x = (i<NN)? cnt[i] : 0;
  int incl = block_scan_incl(x, wsum);
  if(i<NN) offs[i] = bpre[blockIdx.x] + incl - x;
}

// atomic-free scatter: csr[offs[c]+pos[e]] = (row, ew)
__global__ __launch_bounds__(256) void k_scatter(const int* __restrict__ ei, const float* __restrict__ ew,
                                                 const int* __restrict__ offs, const int* __restrict__ pos,
                                                 int2* __restrict__ csr){
  int e = blockIdx.x*256+threadIdx.x;
  if(e<NE){
    int c = ei[NE+e];
    int2 v; v.x = ei[e]; v.y = __float_as_int(ew[e]);
    csr[offs[c]+pos[e]] = v;
  }
}

// deg = 1 + row-sum of ew (atomic-free), dis = rsqrt(deg)  [deg>=1 always]
__global__ __launch_bounds__(256) void k_deg(const int2* __restrict__ csr, const int* __restrict__ offs,
                                             float* dis){
  int i = blockIdx.x*256+threadIdx.x;
  if(i<NN){
    float s = 1.f;
    int e0=offs[i], e1=offs[i+1];
    for(int j=e0;j<e1;j++) s += __int_as_float(csr[j].y);
    dis[i] = rsqrtf(s);
  }
}

// patch edge norm in place: y = dis[r]*ew   (dis[c] factored out in k_agg)
__global__ __launch_bounds__(256) void k_normE(int2* __restrict__ csr, const float* __restrict__ dis){
  int j = blockIdx.x*256+threadIdx.x;
  if(j<NE){
    int2 v = csr[j];
    v.y = __float_as_int(dis[v.x]*__int_as_float(v.y));
    csr[j] = v;
  }
}

// ---------------- layer-0 matmul: wave = feature slice (uniform), lane = node ----------------
// A row per node = 144 words (576B): feature f at word offset f*3, bf16 [t6].
__global__ __launch_bounds__(256) void k_mm0(const float* __restrict__ X, const float* __restrict__ W,
                                             unsigned* __restrict__ A){
  int s = __builtin_amdgcn_readfirstlane(threadIdx.x>>6);   // 0..3, wave-uniform
  int n = blockIdx.x*64 + (threadIdx.x&63);
  if(n>=NN) return;
  const float* xb = X + (long long)n*64;
  const float* wb = W + 12*s;
  float acc[TT][12];
#pragma unroll
  for(int t=0;t<TT;t++)
#pragma unroll
    for(int j=0;j<12;j++) acc[t][j]=0.f;
#pragma unroll 2
  for(int k4=0;k4<16;k4++){
    float4 xv[TT];
#pragma unroll
    for(int t=0;t<TT;t++) xv[t] = *reinterpret_cast<const float4*>(xb + (long long)t*NN*64 + 4*k4);
#pragma unroll
    for(int q=0;q<4;q++){
      const float* wr = wb + (4*k4+q)*HID;
      float w[12];
#pragma unroll
      for(int j=0;j<12;j++) w[j]=wr[j];   // uniform addr -> s_load
#pragma unroll
      for(int t=0;t<TT;t++){
        float xs = (&xv[t].x)[q];
#pragma unroll
        for(int j=0;j<12;j++) acc[t][j] = fmaf(xs, w[j], acc[t][j]);
      }
    }
  }
  unsigned buf[36];
#pragma unroll
  for(int j=0;j<12;j++){
    buf[3*j  ]=pack2(acc[0][j],acc[1][j]);
    buf[3*j+1]=pack2(acc[2][j],acc[3][j]);
    buf[3*j+2]=pack2(acc[4][j],acc[5][j]);
  }
  uint4* o4 = reinterpret_cast<uint4*>(A + (long long)n*144 + 36*s);
#pragma unroll
  for(int q=0;q<9;q++) o4[q] = make_uint4(buf[4*q],buf[4*q+1],buf[4*q+2],buf[4*q+3]);
}

// ---------------- layer-1 matmul (K=48), input fp32 [n][t][48] ----------------
__global__ __launch_bounds__(256) void k_mm1(const float* __restrict__ X, const float* __restrict__ W,
                                             unsigned* __restrict__ A){
  int s = __builtin_amdgcn_readfirstlane(threadIdx.x>>6);
  int n = blockIdx.x*64 + (threadIdx.x&63);
  if(n>=NN) return;
  const float* xb = X + (long long)n*(TT*HID);
  const float* wb = W + 12*s;
  float acc[TT][12];
#pragma unroll
  for(int t=0;t<TT;t++)
#pragma unroll
    for(int j=0;j<12;j++) acc[t][j]=0.f;
#pragma unroll 2
  for(int k4=0;k4<12;k4++){
    float4 xv[TT];
#pragma unroll
    for(int t=0;t<TT;t++) xv[t] = *reinterpret_cast<const float4*>(xb + t*HID + 4*k4);
#pragma unroll
    for(int q=0;q<4;q++){
      const float* wr = wb + (4*k4+q)*HID;
      float w[12];
#pragma unroll
      for(int j=0;j<12;j++) w[j]=wr[j];
#pragma unroll
      for(int t=0;t<TT;t++){
        float xs = (&xv[t].x)[q];
#pragma unroll
        for(int j=0;j<12;j++) acc[t][j] = fmaf(xs, w[j], acc[t][j]);
      }
    }
  }
  unsigned buf[36];
#pragma unroll
  for(int j=0;j<12;j++){
    buf[3*j  ]=pack2(acc[0][j],acc[1][j]);
    buf[3*j+1]=pack2(acc[2][j],acc[3][j]);
    buf[3*j+2]=pack2(acc[4][j],acc[5][j]);
  }
  uint4* o4 = reinterpret_cast<uint4*>(A + (long long)n*144 + 36*s);
#pragma unroll
  for(int q=0;q<9;q++) o4[q] = make_uint4(buf[4*q],buf[4*q+1],buf[4*q+2],buf[4*q+3]);
}

// ---------------- CSR aggregation (bf16 gather) + bias + LN + ReLU (+resid)
// edge norm stored = dis[r]*ew ; dis[c] factored: out = dn*(Σ nr*x_r + dn*x_c)
__global__ __launch_bounds__(256) void k_agg(const unsigned* __restrict__ A, const float* __restrict__ bias,
                                             const float* __restrict__ gain, const float* __restrict__ beta,
                                             const float* __restrict__ resid, float* __restrict__ out,
                                             const int* __restrict__ offs, const int2* __restrict__ csr,
                                             const float* __restrict__ dis){
  int wid = (blockIdx.x*256+threadIdx.x)>>6;
  int lane = threadIdx.x & 63;
  if(wid>=NN) return;
  const bool act = lane<HID;
  const int f = act? lane : (HID-1);
  float dn = dis[wid];
  float acc[TT];
  {
    U3 v = *reinterpret_cast<const U3*>(A + (long long)wid*144 + 3*f);
    acc[0]=dn*bflo(v.x); acc[1]=dn*bfhi(v.x);
    acc[2]=dn*bflo(v.y); acc[3]=dn*bfhi(v.y);
    acc[4]=dn*bflo(v.z); acc[5]=dn*bfhi(v.z);
  }
  int e0=offs[wid], e1=offs[wid+1];
  int e=e0;
  for(; e+3<e1; e+=4){
    int2 i0=csr[e], i1=csr[e+1], i2=csr[e+2], i3=csr[e+3];
    U3 d0 = *reinterpret_cast<const U3*>(A + (long long)i0.x*144 + 3*f);
    U3 d1 = *reinterpret_cast<const U3*>(A + (long long)i1.x*144 + 3*f);
    U3 d2 = *reinterpret_cast<const U3*>(A + (long long)i2.x*144 + 3*f);
    U3 d3 = *reinterpret_cast<const U3*>(A + (long long)i3.x*144 + 3*f);
    float n0=__int_as_float(i0.y), n1=__int_as_float(i1.y);
    float n2=__int_as_float(i2.y), n3=__int_as_float(i3.y);
    acc[0]=fmaf(n0,bflo(d0.x),acc[0]); acc[1]=fmaf(n0,bfhi(d0.x),acc[1]);
    acc[2]=fmaf(n0,bflo(d0.y),acc[2]); acc[3]=fmaf(n0,bfhi(d0.y),acc[3]);
    acc[4]=fmaf(n0,bflo(d0.z),acc[4]); acc[5]=fmaf(n0,bfhi(d0.z),acc[5]);
    acc[0]=fmaf(n1,bflo(d1.x),acc[0]); acc[1]=fmaf(n1,bfhi(d1.x),acc[1]);
    acc[2]=fmaf(n1,bflo(d1.y),acc[2]); acc[3]=fmaf(n1,bfhi(d1.y),acc[3]);
    acc[4]=fmaf(n1,bflo(d1.z),acc[4]); acc[5]=fmaf(n1,bfhi(d1.z),acc[5]);
    acc[0]=fmaf(n2,bflo(d2.x),acc[0]); acc[1]=fmaf(n2,bfhi(d2.x),acc[1]);
    acc[2]=fmaf(n2,bflo(d2.y),acc[2]); acc[3]=fmaf(n2,bfhi(d2.y),acc[3]);
    acc[4]=fmaf(n2,bflo(d2.z),acc[4]); acc[5]=fmaf(n2,bfhi(d2.z),acc[5]);
    acc[0]=fmaf(n3,bflo(d3.x),acc[0]); acc[1]=fmaf(n3,bfhi(d3.x),acc[1]);
    acc[2]=fmaf(n3,bflo(d3.y),acc[2]); acc[3]=fmaf(n3,bfhi(d3.y),acc[3]);
    acc[4]=fmaf(n3,bflo(d3.z),acc[4]); acc[5]=fmaf(n3,bfhi(d3.z),acc[5]);
  }
  for(; e<e1; ++e){
    int2 i0=csr[e];
    U3 d0 = *reinterpret_cast<const U3*>(A + (long long)i0.x*144 + 3*f);
    float n0=__int_as_float(i0.y);
    acc[0]=fmaf(n0,bflo(d0.x),acc[0]); acc[1]=fmaf(n0,bfhi(d0.x),acc[1]);
    acc[2]=fmaf(n0,bflo(d0.y),acc[2]); acc[3]=fmaf(n0,bfhi(d0.y),acc[3]);
    acc[4]=fmaf(n0,bflo(d0.z),acc[4]); acc[5]=fmaf(n0,bfhi(d0.z),acc[5]);
  }
  float bb = bias[f], gg = gain[f], be = beta[f];
  const float rn = 1.0f/HID;
#pragma unroll
  for(int t=0;t<TT;t++){
    float val = fmaf(acc[t], dn, bb);    // final *dn fold
    float v = act? val : 0.f;
    float s = v, s2 = v*v;
#pragma unroll
    for(int m=32;m>=1;m>>=1){
      s  += __shfl_xor(s,  m, 64);
      s2 += __shfl_xor(s2, m, 64);
    }
    float mu  = s*rn;
    float var = fmaxf(s2*rn - mu*mu, 0.f);
    float y = (val-mu)*rsqrtf(var+1e-5f)*gg + be;
    y = fmaxf(y, 0.f);
    long long oidx = (long long)wid*(TT*HID) + t*HID + f;
    if(resid) y += resid[oidx];
    if(act) out[oidx] = y;
  }
}

// ---------------- x-side GRU GEMM (parallel, barrier-free) ----------------
// gi[t][gf pair p][n] packed fp16: lo=gf 2p, hi=gf 2p+1.  gi = x @ W_ih^T + b_ih.
// block = 64 nodes x 6 waves, wave = timestep, lane = node.
__global__ __launch_bounds__(384) void k_gi(const float* __restrict__ X,     // h2 [n][t][48]
                                            const float* __restrict__ WxT,   // [48][144]
                                            const float* __restrict__ bih,
                                            unsigned* __restrict__ gi){
  int wv = __builtin_amdgcn_readfirstlane(threadIdx.x>>6);   // 0..5 = t
  int lane = threadIdx.x & 63;
  long long n = (long long)blockIdx.x*64 + lane;
  long long gn = (n < NN)? n : (NN-1);
  const float* xb = X + gn*(TT*HID) + wv*HID;
  const bool wr = (n < NN);
#pragma unroll 1
  for(int g2=0; g2<6; g2++){           // 6 passes of 24 gate-features
    float acc[24];
#pragma unroll
    for(int j=0;j<24;j++) acc[j] = bih[g2*24+j];
#pragma unroll 2
    for(int k4=0;k4<12;k4++){
      float4 xv = *reinterpret_cast<const float4*>(xb + 4*k4);
#pragma unroll
      for(int q=0;q<4;q++){
        const float* wp = WxT + (4*k4+q)*144 + g2*24;
        float ws[24];
#pragma unroll
        for(int j=0;j<24;j++) ws[j]=wp[j];          // uniform -> s_load
        float xs = (&xv.x)[q];
#pragma unroll
        for(int j=0;j<24;j++) acc[j]=fmaf(xs, ws[j], acc[j]);
      }
    }
    if(wr){
      unsigned* ob = gi + ((long long)(wv*72 + g2*12))*NN + n;
#pragma unroll
      for(int m=0;m<12;m++){
        unsigned u = f2h(acc[2*m]) | (f2h(acc[2*m+1])<<16);
        ob[(long long)m*NN] = u;                    // lane-stride-1, coalesced
      }
    }
  }
}

// ---------------- h-side recurrence (6 steps) + classifier ----------------
// block: 64 nodes, 384 threads = 6 waves. Wave wv owns 8 features, lane = node.
// h double-buffered in LDS [2][48][65]; ONE barrier per step. h_old carried in regs.
__global__ __launch_bounds__(384) void k_gruH(const unsigned* __restrict__ gi,
                                              const float* __restrict__ Whg,  // [6][48][24]
                                              const float* __restrict__ bhh,
                                              const float* __restrict__ Wc1, const float* __restrict__ bc1,
                                              const float* __restrict__ Wc2, const float* __restrict__ bc2,
                                              float* __restrict__ out){
  __shared__ float hbuf[2][48*LR];
  int tid = threadIdx.x;
  int wv = __builtin_amdgcn_readfirstlane(tid>>6);   // 0..5, uniform
  int lane = tid & 63;
  int f0 = wv*8;
  long long n = (long long)blockIdx.x*64 + lane;
  long long gn = (n<NN)? n : (NN-1);

  for(int i=tid;i<48*LR;i+=384) hbuf[0][i]=0.f;

  float rb[8], zb[8], nb[8], hprev[8];
#pragma unroll
  for(int j=0;j<8;j++){
    rb[j]=bhh[f0+j]; zb[j]=bhh[48+f0+j]; nb[j]=bhh[96+f0+j];
    hprev[j]=0.f;
  }
  __syncthreads();

  int cur=0;
  for(int t=0;t<TT;t++){
    // issue gi loads early; latency hides under the k-loop
    const unsigned* gb = gi + (long long)t*72*NN + gn;
    unsigned gpk[12];
#pragma unroll
    for(int m=0;m<4;m++){
      gpk[m]   = gb[(long long)(      f0/2+m)*NN];
      gpk[4+m] = gb[(long long)(24 +  f0/2+m)*NN];
      gpk[8+m] = gb[(long long)(48 +  f0/2+m)*NN];
    }
    float ra[8], za[8], ha[8];
#pragma unroll
    for(int j=0;j<8;j++){ ra[j]=0.f; za[j]=0.f; ha[j]=0.f; }
    const float* hb = &hbuf[cur][0];
#pragma unroll 4
    for(int k=0;k<48;k++){
      const float* wp = Whg + (wv*48+k)*24;
      float ws[24];
#pragma unroll
      for(int q=0;q<24;q++) ws[q]=wp[q];            // uniform -> s_load (24/iter)
      float hk = hb[k*LR+lane];
#pragma unroll
      for(int j=0;j<8;j++){
        ra[j]=fmaf(hk,ws[j],   ra[j]);
        za[j]=fmaf(hk,ws[8+j], za[j]);
        ha[j]=fmaf(hk,ws[16+j],ha[j]);
      }
    }
    float* hw = &hbuf[cur^1][0];
#pragma unroll
    for(int j=0;j<8;j++){
      unsigned pr=gpk[j>>1], pz=gpk[4+(j>>1)], pn=gpk[8+(j>>1)];
      float gir = (j&1)? h2f(pr>>16) : h2f(pr);
      float giz = (j&1)? h2f(pz>>16) : h2f(pz);
      float gin = (j&1)? h2f(pn>>16) : h2f(pn);
      float r  = sigmoidf_(ra[j]+rb[j]+gir);
      float zg = sigmoidf_(za[j]+zb[j]+giz);
      float ng = tanhf_(gin + r*(ha[j]+nb[j]));
      float hv = (1.f-zg)*ng + zg*hprev[j];
      hprev[j]=hv;
      hw[(f0+j)*LR+lane]=hv;
    }
    __syncthreads();   // next buffer fully written
    cur^=1;
  }

  // classifier epilogue: wave 0 covers the block's 64 nodes
  if(wv==0 && n<NN){
    const float* hb=&hbuf[cur][0];
    float hv[24];
#pragma unroll
    for(int j=0;j<24;j++) hv[j]=bc1[j];
    for(int k=0;k<HID;k++){
      float xk = hb[k*LR+lane];
      const float* wr2 = Wc1 + k*24;   // uniform -> s_load
#pragma unroll
      for(int j=0;j<24;j++) hv[j] = fmaf(xk, wr2[j], hv[j]);
    }
    float l0=bc2[0], l1=bc2[1];
#pragma unroll
    for(int j=0;j<24;j++){
      float a = fmaxf(hv[j],0.f);
      l0 = fmaf(a, Wc2[2*j],   l0);
      l1 = fmaf(a, Wc2[2*j+1], l1);
    }
    reinterpret_cast<float2*>(out)[n] = make_float2(l0,l1);
  }
}

static inline size_t al256(size_t x){ return (x+255)&~(size_t)255; }

extern "C" void kernel_launch(void* const* d_in, const int* in_sizes, int n_in,
                              void* d_out, int out_size, void* d_ws, size_t ws_size,
                              hipStream_t stream){
  const float* x_seq=(const float*)d_in[0];
  const int*   ei   =(const int*)d_in[1];
  const float* ew   =(const float*)d_in[2];
  const float* W0=(const float*)d_in[3];  const float* b0=(const float*)d_in[4];
  const float* g0=(const float*)d_in[5];  const float* be0=(const float*)d_in[6];
  const float* W1=(const float*)d_in[7];  const float* b1=(const float*)d_in[8];
  const float* g1=(const float*)d_in[9];  const float* be1=(const float*)d_in[10];
  const float* Wih=(const float*)d_in[11];const float* Whh=(const float*)d_in[12];
  const float* bih=(const float*)d_in[13];const float* bhh=(const float*)d_in[14];
  const float* Wc1=(const float*)d_in[15];const float* bc1=(const float*)d_in[16];
  const float* Wc2=(const float*)d_in[17];const float* bc2=(const float*)d_in[18];
  float* outp=(float*)d_out;

  char* p=(char*)d_ws; size_t off=0;
  auto alloc=[&](size_t bytes)->void*{ void* r=p+off; off=al256(off+bytes); return r; };
  float* dis    =(float*)alloc((size_t)NN*4);
  int*   cnt    =(int*)  alloc((size_t)NN*4);
  int*   offs   =(int*)  alloc((size_t)(NN+1)*4);
  int*   bsum   =(int*)  alloc((size_t)NB*4);
  int*   bpre   =(int*)  alloc((size_t)NB*4);
  int*   pos    =(int*)  alloc((size_t)NE*4);
  int2*  csr    =(int2*) alloc((size_t)NE*8);
  float* WxT    =(float*)alloc((size_t)48*144*4);
  float* Whg    =(float*)alloc((size_t)6*48*24*4);
  unsigned* A   =(unsigned*)alloc((size_t)NN*576 + 1024);   // bf16 [n][f][t6], 576B/row
  float* h1     =(float*)alloc((size_t)NN*TT*HID*4);
  float* h2     =(float*)alloc((size_t)NN*TT*HID*4);
  // gi [6][72][NN] u32 = 86,400,000 B aliases A (28,801,024 B) + h1 (57,600,000 B)
  // = 86,401,024 contiguous bytes; both are dead once the second k_agg has run.
  unsigned* gi  =(unsigned*)A;

  const int GN=(NN+255)/256, GE=(NE+255)/256;
  const int GMM=(NN+63)/64;              // 64 nodes/block
  const int GAGG=(NN*64+255)/256;        // 1 wave/node
  const int GGRU=(NN+63)/64;             // 64 nodes/block, 6 waves

  k_setup  <<<GN,256,0,stream>>>(cnt,Wih,Whh,WxT,Whg);
  k_cnt    <<<GE,256,0,stream>>>(ei,cnt,pos);
  k_partA  <<<NB,256,0,stream>>>(cnt,bsum);
  k_midB   <<<1,256,0,stream>>>(bsum,bpre,offs);
  k_offsC  <<<NB,256,0,stream>>>(cnt,bpre,offs);
  k_scatter<<<GE,256,0,stream>>>(ei,ew,offs,pos,csr);
  k_deg    <<<GN,256,0,stream>>>(csr,offs,dis);
  k_normE  <<<GE,256,0,stream>>>(csr,dis);

  // layer 0
  k_mm0<<<GMM,256,0,stream>>>(x_seq, W0, A);
  k_agg<<<GAGG,256,0,stream>>>(A,b0,g0,be0,nullptr,h1,offs,csr,dis);
  // layer 1 (residual = h1)
  k_mm1<<<GMM,256,0,stream>>>(h1, W1, A);
  k_agg<<<GAGG,256,0,stream>>>(A,b1,g1,be1,h1,h2,offs,csr,dis);
  // GRU: parallel x-side GEMM, then h-side recurrence + classifier
  k_gi  <<<GMM,384,0,stream>>>(h2, WxT, bih, gi);
  k_gruH<<<GGRU,384,0,stream>>>(gi, Whg, bhh, Wc1,bc1,Wc2,bc2, outp);
}

// Round 3
// 699.603 us; speedup vs baseline: 1.0806x; 1.0806x over previous
//
#include <hip/hip_runtime.h>
#include <hip/hip_fp16.h>
#include <math.h>

#define NN 50000
#define NE 800000
#define TT 6
#define HID 48
#define NB 196   // (NN+255)/256
#define LR 65    // LDS row stride for 64 nodes (mod 32 == 1 -> conflict-free)

__device__ __forceinline__ float sigmoidf_(float x){ return 1.0f/(1.0f+__expf(-x)); }
__device__ __forceinline__ float tanhf_(float x){
  float xc = fminf(fmaxf(x,-15.f),15.f);
  float t = __expf(2.f*xc);
  return (t-1.f)/(t+1.f);
}
__device__ __forceinline__ unsigned f2bf(float x){
  unsigned u = __float_as_uint(x);
  return (u + 0x7fffu + ((u>>16)&1u)) >> 16;   // RNE to bf16
}
__device__ __forceinline__ unsigned pack2(float a, float b){
  return f2bf(a) | (f2bf(b)<<16);
}
__device__ __forceinline__ float bflo(unsigned u){ return __uint_as_float(u<<16); }
__device__ __forceinline__ float bfhi(unsigned u){ return __uint_as_float(u & 0xffff0000u); }
__device__ __forceinline__ unsigned f2h(float x){
  return (unsigned)__half_as_ushort(__float2half(x));   // RNE fp16
}
__device__ __forceinline__ float h2f(unsigned u){
  return __half2float(__ushort_as_half((unsigned short)(u & 0xffffu)));
}
__device__ __forceinline__ unsigned pack2h(float a, float b){   // RNE fp16 pair
  return f2h(a) | (f2h(b)<<16);
}

typedef __fp16 h2t __attribute__((ext_vector_type(2)));

__device__ __forceinline__ unsigned pkrtz(float a, float b){    // fast packed cvt (RTZ)
#if __has_builtin(__builtin_amdgcn_cvt_pkrtz)
  auto r = __builtin_amdgcn_cvt_pkrtz(a, b);
  return __builtin_bit_cast(unsigned, r);
#else
  return pack2h(a, b);
#endif
}
// acc += lo(a)*lo(b) + hi(a)*hi(b), fp32 accumulate
__device__ __forceinline__ float dot2f(unsigned a, unsigned b, float c){
#if __has_builtin(__builtin_amdgcn_fdot2)
  return __builtin_amdgcn_fdot2(__builtin_bit_cast(h2t, a), __builtin_bit_cast(h2t, b), c, false);
#else
  h2t av = __builtin_bit_cast(h2t, a), bv = __builtin_bit_cast(h2t, b);
  return c + (float)av[0]*(float)bv[0] + (float)av[1]*(float)bv[1];
#endif
}

struct U3 { unsigned x,y,z; };

// 256-thread inclusive block scan (4 waves of 64)
__device__ __forceinline__ int block_scan_incl(int x, int* wsum){
  int lane = threadIdx.x & 63, w = threadIdx.x >> 6;
  int v = x;
#pragma unroll
  for(int d=1; d<64; d<<=1){
    int u = __shfl_up(v, d, 64);
    if(lane >= d) v += u;
  }
  if(lane==63) wsum[w] = v;
  __syncthreads();
  int add = 0;
#pragma unroll
  for(int k=0;k<3;k++) if(w>k) add += wsum[k];
  return v + add;
}

// ---------------- setup: cnt init + GRU weight repack (fp16 pairs along k) ----------------
// Wxp [24 k2][144 gf] u32: pair (Wih[gf][2k2], Wih[gf][2k2+1])
// Whp [6 wv][24 k2][24 c] u32: c<8 -> r-row (wv*8+c), c<16 -> z-row (48+...), else n-row (96+...)
__global__ __launch_bounds__(256) void k_setup(int* cnt,
                                               const float* __restrict__ Wih, const float* __restrict__ Whh,
                                               unsigned* Wxp, unsigned* Whp){
  int i = blockIdx.x*256+threadIdx.x;
  if(i<NN) cnt[i]=0;
  if(i < 24*144){
    int k2 = i/144, gf = i%144;
    Wxp[i] = pack2h(Wih[gf*48 + 2*k2], Wih[gf*48 + 2*k2 + 1]);
  }
  if(i < 6*24*24){
    int wv = i/576, r = i%576;
    int k2 = r/24, c = r%24;
    int row = (c<8) ? (wv*8 + c) : (c<16) ? (48 + wv*8 + c-8) : (96 + wv*8 + c-16);
    Whp[i] = pack2h(Whh[row*48 + 2*k2], Whh[row*48 + 2*k2 + 1]);
  }
}

// single atomic per edge: rank within destination bucket
__global__ __launch_bounds__(256) void k_cnt(const int* __restrict__ ei, int* cnt, int* pos){
  int e = blockIdx.x*256+threadIdx.x;
  if(e<NE){
    int c = ei[NE+e];
    pos[e] = atomicAdd(&cnt[c], 1);
  }
}

// phase A: per-block sums of cnt
__global__ __launch_bounds__(256) void k_partA(const int* __restrict__ cnt, int* bsum){
  __shared__ int wsum[4];
  int i = blockIdx.x*256+threadIdx.x;
  int x = (i<NN)? cnt[i] : 0;
  int lane = threadIdx.x & 63, w = threadIdx.x >> 6;
  int v = x;
#pragma unroll
  for(int m=32;m>=1;m>>=1) v += __shfl_xor(v, m, 64);
  if(lane==0) wsum[w]=v;
  __syncthreads();
  if(threadIdx.x==0) bsum[blockIdx.x] = wsum[0]+wsum[1]+wsum[2]+wsum[3];
}

// phase B: exclusive scan of 196 block sums
__global__ __launch_bounds__(256) void k_midB(const int* __restrict__ bsum, int* bpre, int* offs){
  __shared__ int wsum[4];
  int t = threadIdx.x;
  int x = (t<NB)? bsum[t] : 0;
  int incl = block_scan_incl(x, wsum);
  if(t<NB) bpre[t] = incl - x;
  if(t==255) offs[NN] = incl;   // total
}

// phase C: per-block exclusive scan of cnt + bpre -> offs
__global__ __launch_bounds__(256) void k_offsC(const int* __restrict__ cnt, const int* __restrict__ bpre,
                                               int* offs){
  __shared__ int wsum[4];
  int i = blockIdx.x*256+threadIdx.x;
  int x = (i<NN)? cnt[i] : 0;
  int incl = block_scan_incl(x, wsum);
  if(i<NN) offs[i] = bpre[blockIdx.x] + incl - x;
}

// atomic-free scatter: csr[offs[c]+pos[e]] = (row, ew)
__global__ __launch_bounds__(256) void k_scatter(const int* __restrict__ ei, const float* __restrict__ ew,
                                                 const int* __restrict__ offs, const int* __restrict__ pos,
                                                 int2* __restrict__ csr){
  int e = blockIdx.x*256+threadIdx.x;
  if(e<NE){
    int c = ei[NE+e];
    int2 v; v.x = ei[e]; v.y = __float_as_int(ew[e]);
    csr[offs[c]+pos[e]] = v;
  }
}

// deg = 1 + row-sum of ew (atomic-free), dis = rsqrt(deg)  [deg>=1 always]
__global__ __launch_bounds__(256) void k_deg(const int2* __restrict__ csr, const int* __restrict__ offs,
                                             float* dis){
  int i = blockIdx.x*256+threadIdx.x;
  if(i<NN){
    float s = 1.f;
    int e0=offs[i], e1=offs[i+1];
    for(int j=e0;j<e1;j++) s += __int_as_float(csr[j].y);
    dis[i] = rsqrtf(s);
  }
}

// patch edge norm in place: y = dis[r]*ew   (dis[c] factored out in k_agg)
__global__ __launch_bounds__(256) void k_normE(int2* __restrict__ csr, const float* __restrict__ dis){
  int j = blockIdx.x*256+threadIdx.x;
  if(j<NE){
    int2 v = csr[j];
    v.y = __float_as_int(dis[v.x]*__int_as_float(v.y));
    csr[j] = v;
  }
}

// ---------------- layer-0 matmul: wave = feature slice (uniform), lane = node ----------------
// A row per node = 144 words (576B): feature f at word offset f*3, bf16 [t6].
__global__ __launch_bounds__(256) void k_mm0(const float* __restrict__ X, const float* __restrict__ W,
                                             unsigned* __restrict__ A){
  int s = __builtin_amdgcn_readfirstlane(threadIdx.x>>6);   // 0..3, wave-uniform
  int n = blockIdx.x*64 + (threadIdx.x&63);
  if(n>=NN) return;
  const float* xb = X + (long long)n*64;
  const float* wb = W + 12*s;
  float acc[TT][12];
#pragma unroll
  for(int t=0;t<TT;t++)
#pragma unroll
    for(int j=0;j<12;j++) acc[t][j]=0.f;
#pragma unroll 2
  for(int k4=0;k4<16;k4++){
    float4 xv[TT];
#pragma unroll
    for(int t=0;t<TT;t++) xv[t] = *reinterpret_cast<const float4*>(xb + (long long)t*NN*64 + 4*k4);
#pragma unroll
    for(int q=0;q<4;q++){
      const float* wr = wb + (4*k4+q)*HID;
      float w[12];
#pragma unroll
      for(int j=0;j<12;j++) w[j]=wr[j];   // uniform addr -> s_load
#pragma unroll
      for(int t=0;t<TT;t++){
        float xs = (&xv[t].x)[q];
#pragma unroll
        for(int j=0;j<12;j++) acc[t][j] = fmaf(xs, w[j], acc[t][j]);
      }
    }
  }
  unsigned buf[36];
#pragma unroll
  for(int j=0;j<12;j++){
    buf[3*j  ]=pack2(acc[0][j],acc[1][j]);
    buf[3*j+1]=pack2(acc[2][j],acc[3][j]);
    buf[3*j+2]=pack2(acc[4][j],acc[5][j]);
  }
  uint4* o4 = reinterpret_cast<uint4*>(A + (long long)n*144 + 36*s);
#pragma unroll
  for(int q=0;q<9;q++) o4[q] = make_uint4(buf[4*q],buf[4*q+1],buf[4*q+2],buf[4*q+3]);
}

// ---------------- layer-1 matmul (K=48), input fp32 [n][t][48] ----------------
__global__ __launch_bounds__(256) void k_mm1(const float* __restrict__ X, const float* __restrict__ W,
                                             unsigned* __restrict__ A){
  int s = __builtin_amdgcn_readfirstlane(threadIdx.x>>6);
  int n = blockIdx.x*64 + (threadIdx.x&63);
  if(n>=NN) return;
  const float* xb = X + (long long)n*(TT*HID);
  const float* wb = W + 12*s;
  float acc[TT][12];
#pragma unroll
  for(int t=0;t<TT;t++)
#pragma unroll
    for(int j=0;j<12;j++) acc[t][j]=0.f;
#pragma unroll 2
  for(int k4=0;k4<12;k4++){
    float4 xv[TT];
#pragma unroll
    for(int t=0;t<TT;t++) xv[t] = *reinterpret_cast<const float4*>(xb + t*HID + 4*k4);
#pragma unroll
    for(int q=0;q<4;q++){
      const float* wr = wb + (4*k4+q)*HID;
      float w[12];
#pragma unroll
      for(int j=0;j<12;j++) w[j]=wr[j];
#pragma unroll
      for(int t=0;t<TT;t++){
        float xs = (&xv[t].x)[q];
#pragma unroll
        for(int j=0;j<12;j++) acc[t][j] = fmaf(xs, w[j], acc[t][j]);
      }
    }
  }
  unsigned buf[36];
#pragma unroll
  for(int j=0;j<12;j++){
    buf[3*j  ]=pack2(acc[0][j],acc[1][j]);
    buf[3*j+1]=pack2(acc[2][j],acc[3][j]);
    buf[3*j+2]=pack2(acc[4][j],acc[5][j]);
  }
  uint4* o4 = reinterpret_cast<uint4*>(A + (long long)n*144 + 36*s);
#pragma unroll
  for(int q=0;q<9;q++) o4[q] = make_uint4(buf[4*q],buf[4*q+1],buf[4*q+2],buf[4*q+3]);
}

// ---------------- CSR aggregation (bf16 gather) + bias + LN + ReLU (+resid)
// edge norm stored = dis[r]*ew ; dis[c] factored: out = dn*(Σ nr*x_r + dn*x_c)
__global__ __launch_bounds__(256) void k_agg(const unsigned* __restrict__ A, const float* __restrict__ bias,
                                             const float* __restrict__ gain, const float* __restrict__ beta,
                                             const float* __restrict__ resid, float* __restrict__ out,
                                             const int* __restrict__ offs, const int2* __restrict__ csr,
                                             const float* __restrict__ dis){
  int wid = (blockIdx.x*256+threadIdx.x)>>6;
  int lane = threadIdx.x & 63;
  if(wid>=NN) return;
  const bool act = lane<HID;
  const int f = act? lane : (HID-1);
  float dn = dis[wid];
  float acc[TT];
  {
    U3 v = *reinterpret_cast<const U3*>(A + (long long)wid*144 + 3*f);
    acc[0]=dn*bflo(v.x); acc[1]=dn*bfhi(v.x);
    acc[2]=dn*bflo(v.y); acc[3]=dn*bfhi(v.y);
    acc[4]=dn*bflo(v.z); acc[5]=dn*bfhi(v.z);
  }
  int e0=offs[wid], e1=offs[wid+1];
  int e=e0;
  for(; e+3<e1; e+=4){
    int2 i0=csr[e], i1=csr[e+1], i2=csr[e+2], i3=csr[e+3];
    U3 d0 = *reinterpret_cast<const U3*>(A + (long long)i0.x*144 + 3*f);
    U3 d1 = *reinterpret_cast<const U3*>(A + (long long)i1.x*144 + 3*f);
    U3 d2 = *reinterpret_cast<const U3*>(A + (long long)i2.x*144 + 3*f);
    U3 d3 = *reinterpret_cast<const U3*>(A + (long long)i3.x*144 + 3*f);
    float n0=__int_as_float(i0.y), n1=__int_as_float(i1.y);
    float n2=__int_as_float(i2.y), n3=__int_as_float(i3.y);
    acc[0]=fmaf(n0,bflo(d0.x),acc[0]); acc[1]=fmaf(n0,bfhi(d0.x),acc[1]);
    acc[2]=fmaf(n0,bflo(d0.y),acc[2]); acc[3]=fmaf(n0,bfhi(d0.y),acc[3]);
    acc[4]=fmaf(n0,bflo(d0.z),acc[4]); acc[5]=fmaf(n0,bfhi(d0.z),acc[5]);
    acc[0]=fmaf(n1,bflo(d1.x),acc[0]); acc[1]=fmaf(n1,bfhi(d1.x),acc[1]);
    acc[2]=fmaf(n1,bflo(d1.y),acc[2]); acc[3]=fmaf(n1,bfhi(d1.y),acc[3]);
    acc[4]=fmaf(n1,bflo(d1.z),acc[4]); acc[5]=fmaf(n1,bfhi(d1.z),acc[5]);
    acc[0]=fmaf(n2,bflo(d2.x),acc[0]); acc[1]=fmaf(n2,bfhi(d2.x),acc[1]);
    acc[2]=fmaf(n2,bflo(d2.y),acc[2]); acc[3]=fmaf(n2,bfhi(d2.y),acc[3]);
    acc[4]=fmaf(n2,bflo(d2.z),acc[4]); acc[5]=fmaf(n2,bfhi(d2.z),acc[5]);
    acc[0]=fmaf(n3,bflo(d3.x),acc[0]); acc[1]=fmaf(n3,bfhi(d3.x),acc[1]);
    acc[2]=fmaf(n3,bflo(d3.y),acc[2]); acc[3]=fmaf(n3,bfhi(d3.y),acc[3]);
    acc[4]=fmaf(n3,bflo(d3.z),acc[4]); acc[5]=fmaf(n3,bfhi(d3.z),acc[5]);
  }
  for(; e<e1; ++e){
    int2 i0=csr[e];
    U3 d0 = *reinterpret_cast<const U3*>(A + (long long)i0.x*144 + 3*f);
    float n0=__int_as_float(i0.y);
    acc[0]=fmaf(n0,bflo(d0.x),acc[0]); acc[1]=fmaf(n0,bfhi(d0.x),acc[1]);
    acc[2]=fmaf(n0,bflo(d0.y),acc[2]); acc[3]=fmaf(n0,bfhi(d0.y),acc[3]);
    acc[4]=fmaf(n0,bflo(d0.z),acc[4]); acc[5]=fmaf(n0,bfhi(d0.z),acc[5]);
  }
  float bb = bias[f], gg = gain[f], be = beta[f];
  const float rn = 1.0f/HID;
#pragma unroll
  for(int t=0;t<TT;t++){
    float val = fmaf(acc[t], dn, bb);    // final *dn fold
    float v = act? val : 0.f;
    float s = v, s2 = v*v;
#pragma unroll
    for(int m=32;m>=1;m>>=1){
      s  += __shfl_xor(s,  m, 64);
      s2 += __shfl_xor(s2, m, 64);
    }
    float mu  = s*rn;
    float var = fmaxf(s2*rn - mu*mu, 0.f);
    float y = (val-mu)*rsqrtf(var+1e-5f)*gg + be;
    y = fmaxf(y, 0.f);
    long long oidx = (long long)wid*(TT*HID) + t*HID + f;
    if(resid) y += resid[oidx];
    if(act) out[oidx] = y;
  }
}

// ---------------- x-side GRU GEMM v2 (fp16 dot2, single k-sweep) ----------------
// gi[t][gf pair p][n] packed fp16. block = 64 nodes x 6 waves, wave = timestep, lane = node.
// x packed to fp16 pairs once (24 u32, register-resident); 3 column passes of 48;
// weight stream = 13.8 KB total per wave (scalar-cache resident).
__global__ __launch_bounds__(384) void k_gi(const float* __restrict__ X,     // h2 [n][t][48]
                                            const unsigned* __restrict__ Wxp,// [24][144] u32
                                            const float* __restrict__ bih,
                                            unsigned* __restrict__ gi){
  int wv = __builtin_amdgcn_readfirstlane(threadIdx.x>>6);   // 0..5 = t
  int lane = threadIdx.x & 63;
  long long n = (long long)blockIdx.x*64 + lane;
  long long gn = (n < NN)? n : (NN-1);
  const bool wr = (n < NN);
  const float* xb = X + gn*(TT*HID) + wv*HID;
  unsigned xp[24];
#pragma unroll
  for(int q=0;q<12;q++){
    float4 v = *reinterpret_cast<const float4*>(xb + 4*q);
    xp[2*q]   = pkrtz(v.x, v.y);
    xp[2*q+1] = pkrtz(v.z, v.w);
  }
#pragma unroll 1
  for(int pass=0; pass<3; pass++){             // 48 cols per pass
    float acc[48];
#pragma unroll
    for(int j=0;j<48;j++) acc[j] = bih[pass*48+j];
#pragma unroll 2
    for(int k2=0;k2<24;k2++){
      unsigned xk = xp[k2];
#pragma unroll
      for(int c=0;c<2;c++){
        const unsigned* wp = Wxp + k2*144 + pass*48 + c*24;
        unsigned ws[24];
#pragma unroll
        for(int j=0;j<24;j++) ws[j]=wp[j];     // uniform -> s_load
#pragma unroll
        for(int j=0;j<24;j++) acc[c*24+j] = dot2f(xk, ws[j], acc[c*24+j]);
      }
    }
    if(wr){
      unsigned* ob = gi + ((long long)(wv*72 + pass*24))*NN + n;
#pragma unroll
      for(int m=0;m<24;m++){
        ob[(long long)m*NN] = pack2h(acc[2*m], acc[2*m+1]);   // lane-stride-1, coalesced
      }
    }
  }
}

// ---------------- h-side recurrence v2 (fp16 dot2) + classifier ----------------
// block: 64 nodes, 384 threads = 6 waves. Wave wv owns 8 features, lane = node.
// h in LDS as packed fp16 feature-pairs [2][24][64]; hprev fp32 in regs.
// k-loop: 24 iters x (24-u32 s_load + 1 ds_read + 24 dot2) — half the VALU and
// half the scalar bytes of the fp32 version; Whp (13.8 KB) is sK$-resident.
__global__ __launch_bounds__(384) void k_gruH(const unsigned* __restrict__ gi,
                                              const unsigned* __restrict__ Whp, // [6][24][24] u32
                                              const float* __restrict__ bhh,
                                              const float* __restrict__ Wc1, const float* __restrict__ bc1,
                                              const float* __restrict__ Wc2, const float* __restrict__ bc2,
                                              float* __restrict__ out){
  __shared__ unsigned hb[2][24*64];
  int tid = threadIdx.x;
  int wv = __builtin_amdgcn_readfirstlane(tid>>6);   // 0..5, uniform
  int lane = tid & 63;
  int f0 = wv*8;
  long long n = (long long)blockIdx.x*64 + lane;
  long long gn = (n<NN)? n : (NN-1);

  for(int i=tid;i<24*64;i+=384) hb[0][i]=0u;

  float rb[8], zb[8], nb[8], hprev[8];
#pragma unroll
  for(int j=0;j<8;j++){
    rb[j]=bhh[f0+j]; zb[j]=bhh[48+f0+j]; nb[j]=bhh[96+f0+j];
    hprev[j]=0.f;
  }
  __syncthreads();

  int cur=0;
  for(int t=0;t<TT;t++){
    // issue gi loads early; latency hides under the k-loop
    const unsigned* gb = gi + (long long)t*72*NN + gn;
    unsigned gpk[12];
#pragma unroll
    for(int m=0;m<4;m++){
      gpk[m]   = gb[(long long)(      wv*4+m)*NN];
      gpk[4+m] = gb[(long long)(24 +  wv*4+m)*NN];
      gpk[8+m] = gb[(long long)(48 +  wv*4+m)*NN];
    }
    float acc[24];
#pragma unroll
    for(int j=0;j<24;j++) acc[j]=0.f;
    const unsigned* hbc = &hb[cur][0];
#pragma unroll 2
    for(int k2=0;k2<24;k2++){
      const unsigned* wp = Whp + (wv*24+k2)*24;
      unsigned ws[24];
#pragma unroll
      for(int q=0;q<24;q++) ws[q]=wp[q];       // uniform -> s_load
      unsigned h2k = hbc[k2*64+lane];
#pragma unroll
      for(int c=0;c<24;c++) acc[c] = dot2f(h2k, ws[c], acc[c]);
    }
    unsigned* hw = &hb[cur^1][0];
    float hn[8];
#pragma unroll
    for(int j=0;j<8;j++){
      unsigned pr=gpk[j>>1], pz=gpk[4+(j>>1)], pn=gpk[8+(j>>1)];
      float gir = (j&1)? h2f(pr>>16) : h2f(pr);
      float giz = (j&1)? h2f(pz>>16) : h2f(pz);
      float gin = (j&1)? h2f(pn>>16) : h2f(pn);
      float r  = sigmoidf_(acc[j]+rb[j]+gir);
      float zg = sigmoidf_(acc[8+j]+zb[j]+giz);
      float ng = tanhf_(gin + r*(acc[16+j]+nb[j]));
      float hv = (1.f-zg)*ng + zg*hprev[j];
      hprev[j]=hv; hn[j]=hv;
    }
#pragma unroll
    for(int m=0;m<4;m++) hw[(wv*4+m)*64+lane] = pack2h(hn[2*m], hn[2*m+1]);
    __syncthreads();   // next buffer fully written
    cur^=1;
  }

  // classifier epilogue: wave 0 covers the block's 64 nodes
  if(wv==0 && n<NN){
    const unsigned* hbc=&hb[cur][0];
    float hv[24];
#pragma unroll
    for(int j=0;j<24;j++) hv[j]=bc1[j];
    for(int k2=0;k2<24;k2++){
      unsigned u = hbc[k2*64+lane];
      float hk0 = h2f(u), hk1 = h2f(u>>16);
      const float* w0 = Wc1 + (2*k2)*24;     // uniform -> s_load
      const float* w1 = Wc1 + (2*k2+1)*24;
#pragma unroll
      for(int j=0;j<24;j++) hv[j] = fmaf(hk0, w0[j], hv[j]);
#pragma unroll
      for(int j=0;j<24;j++) hv[j] = fmaf(hk1, w1[j], hv[j]);
    }
    float l0=bc2[0], l1=bc2[1];
#pragma unroll
    for(int j=0;j<24;j++){
      float a = fmaxf(hv[j],0.f);
      l0 = fmaf(a, Wc2[2*j],   l0);
      l1 = fmaf(a, Wc2[2*j+1], l1);
    }
    reinterpret_cast<float2*>(out)[n] = make_float2(l0,l1);
  }
}

static inline size_t al256(size_t x){ return (x+255)&~(size_t)255; }

extern "C" void kernel_launch(void* const* d_in, const int* in_sizes, int n_in,
                              void* d_out, int out_size, void* d_ws, size_t ws_size,
                              hipStream_t stream){
  const float* x_seq=(const float*)d_in[0];
  const int*   ei   =(const int*)d_in[1];
  const float* ew   =(const float*)d_in[2];
  const float* W0=(const float*)d_in[3];  const float* b0=(const float*)d_in[4];
  const float* g0=(const float*)d_in[5];  const float* be0=(const float*)d_in[6];
  const float* W1=(const float*)d_in[7];  const float* b1=(const float*)d_in[8];
  const float* g1=(const float*)d_in[9];  const float* be1=(const float*)d_in[10];
  const float* Wih=(const float*)d_in[11];const float* Whh=(const float*)d_in[12];
  const float* bih=(const float*)d_in[13];const float* bhh=(const float*)d_in[14];
  const float* Wc1=(const float*)d_in[15];const float* bc1=(const float*)d_in[16];
  const float* Wc2=(const float*)d_in[17];const float* bc2=(const float*)d_in[18];
  float* outp=(float*)d_out;

  char* p=(char*)d_ws; size_t off=0;
  auto alloc=[&](size_t bytes)->void*{ void* r=p+off; off=al256(off+bytes); return r; };
  float* dis    =(float*)alloc((size_t)NN*4);
  int*   cnt    =(int*)  alloc((size_t)NN*4);
  int*   offs   =(int*)  alloc((size_t)(NN+1)*4);
  int*   bsum   =(int*)  alloc((size_t)NB*4);
  int*   bpre   =(int*)  alloc((size_t)NB*4);
  int*   pos    =(int*)  alloc((size_t)NE*4);
  int2*  csr    =(int2*) alloc((size_t)NE*8);
  unsigned* Wxp =(unsigned*)alloc((size_t)24*144*4);
  unsigned* Whp =(unsigned*)alloc((size_t)6*24*24*4);
  unsigned* A   =(unsigned*)alloc((size_t)NN*576 + 1024);   // bf16 [n][f][t6], 576B/row
  float* h1     =(float*)alloc((size_t)NN*TT*HID*4);
  float* h2     =(float*)alloc((size_t)NN*TT*HID*4);
  // gi [6][72][NN] u32 = 86,400,000 B aliases A (28,801,024 B) + h1 (57,600,000 B)
  // = 86,401,024 contiguous bytes; both are dead once the second k_agg has run.
  unsigned* gi  =(unsigned*)A;

  const int GN=(NN+255)/256, GE=(NE+255)/256;
  const int GMM=(NN+63)/64;              // 64 nodes/block
  const int GAGG=(NN*64+255)/256;        // 1 wave/node
  const int GGRU=(NN+63)/64;             // 64 nodes/block, 6 waves

  k_setup  <<<GN,256,0,stream>>>(cnt,Wih,Whh,Wxp,Whp);
  k_cnt    <<<GE,256,0,stream>>>(ei,cnt,pos);
  k_partA  <<<NB,256,0,stream>>>(cnt,bsum);
  k_midB   <<<1,256,0,stream>>>(bsum,bpre,offs);
  k_offsC  <<<NB,256,0,stream>>>(cnt,bpre,offs);
  k_scatter<<<GE,256,0,stream>>>(ei,ew,offs,pos,csr);
  k_deg    <<<GN,256,0,stream>>>(csr,offs,dis);
  k_normE  <<<GE,256,0,stream>>>(csr,dis);

  // layer 0
  k_mm0<<<GMM,256,0,stream>>>(x_seq, W0, A);
  k_agg<<<GAGG,256,0,stream>>>(A,b0,g0,be0,nullptr,h1,offs,csr,dis);
  // layer 1 (residual = h1)
  k_mm1<<<GMM,256,0,stream>>>(h1, W1, A);
  k_agg<<<GAGG,256,0,stream>>>(A,b1,g1,be1,h1,h2,offs,csr,dis);
  // GRU: parallel x-side GEMM (fp16 dot2), then h-side recurrence + classifier
  k_gi  <<<GMM,384,0,stream>>>(h2, Wxp, bih, gi);
  k_gruH<<<GGRU,384,0,stream>>>(gi, Whp, bhh, Wc1,bc1,Wc2,bc2, outp);
}